// Round 15
// baseline (108.041 us; speedup 1.0000x reference)
//
#include <hip/hip_runtime.h>

typedef unsigned int  u32;
typedef unsigned short u16;

typedef float    f4  __attribute__((ext_vector_type(4)));
typedef short    bf8 __attribute__((ext_vector_type(8)));
typedef __fp16   h8  __attribute__((ext_vector_type(8)));
typedef __fp16   h2  __attribute__((ext_vector_type(2)));

#define NBLK  1024
#define ITERS 4      // 1024 blocks * 4 iters * 64 boards = 262144
#define ZSTR  104    // z1 row stride (u16); 52 dw/row -> b128 starts on 8 disjoint 4-bank groups

// fp32 -> bf16 bits, round-half-up (setup only)
__device__ __forceinline__ u32 bfr(float f) {
    union { float f; u32 u; } v; v.f = f;
    return (v.u + 0x8000u) >> 16;
}
__device__ __forceinline__ u32 pk2(float lo, float hi) { return bfr(lo) | (bfr(hi) << 16); }
__device__ __forceinline__ u32 pkh(float lo, float hi) {   // fp16 pair (RTZ, 1 inst)
    union { h2 h; u32 u; } v; v.h = __builtin_amdgcn_cvt_pkrtz(lo, hi); return v.u;
}
__device__ __forceinline__ u32 nrev(u32 x) {
    return ((x >> 12) & 0xFu) | ((x >> 4) & 0xF0u) | ((x << 4) & 0xF00u) | ((x << 12) & 0xF000u);
}

// ---- phase 1 (waves 0-3 only): build z1 rows + flip flags for wave pw's 16 boards ----
__device__ __forceinline__ void phase1_fn(const int4 e4, u16* __restrict__ z1b, u32* __restrict__ flgb,
                                          const uint2* __restrict__ Th, const uint2* __restrict__ Tv,
                                          const int pw, const int m, const int qd)
{
    u32 pkd = (u32)e4.x | ((u32)e4.y << 4) | ((u32)e4.z << 8) | ((u32)e4.w << 12);
    u32 R0 = (u32)__shfl((int)pkd, m);
    u32 R1 = (u32)__shfl((int)pkd, m + 16);
    u32 R2 = (u32)__shfl((int)pkd, m + 32);
    u32 R3 = (u32)__shfl((int)pkd, m + 48);
    u32 c0v = R0 & 15u, c1v = (R0 >> 12) & 15u, c2v = R3 & 15u, c3v = (R3 >> 12) & 15u;
    u32 best = c0v; int ix = 0;
    if (c1v > best) { best = c1v; ix = 1; }
    if (c2v > best) { best = c2v; ix = 2; }
    if (c3v > best) { best = c3v; ix = 3; }
    const bool fv = (ix >= 2), fh = ((ix & 1) != 0);
    u32 F[4];
    F[0] = fv ? R3 : R0;
    F[1] = fv ? R2 : R1;
    F[2] = fv ? R1 : R2;
    F[3] = fv ? R0 : R3;
    #pragma unroll
    for (int i = 0; i < 4; ++i) F[i] = fh ? nrev(F[i]) : F[i];

    if (qd == 0) flgb[pw*16 + m] = (u32)fv | ((u32)fh << 1);

    const u32 Fq = F[qd];
    u32 nbq[4], nbc[4];
    #pragma unroll
    for (int j = 0; j < 4; ++j) nbq[j] = (Fq >> (4*j)) & 15u;
    #pragma unroll
    for (int i = 0; i < 4; ++i) nbc[i] = (F[i] >> (4*qd)) & 15u;

    uint2 H0 = Th[nbq[0]*11u + nbq[1]];
    uint2 H1 = Th[nbq[1]*11u + nbq[2]];
    uint2 H2 = Th[nbq[2]*11u + nbq[3]];
    uint2 V0 = Tv[nbc[0]*11u + nbc[1]];
    uint2 V1 = Tv[nbc[1]*11u + nbc[2]];
    uint2 V2 = Tv[nbc[2]*11u + nbc[3]];

    u16* zrow = &z1b[(pw*16 + m) * ZSTR];
    *(uint2*)(zrow + (qd*3 + 0)*4) = H0;
    *(uint2*)(zrow + (qd*3 + 1)*4) = H1;
    *(uint2*)(zrow + (qd*3 + 2)*4) = H2;
    *(uint2*)(zrow + 48 + (0*4 + qd)*4) = V0;
    *(uint2*)(zrow + 48 + (1*4 + qd)*4) = V1;
    *(uint2*)(zrow + 48 + (2*4 + qd)*4) = V2;
}

// ---- all waves: GEMM1 (32-feature slice) -> relu/fp16 in-lane -> GEMM2 -> Pb partials ----
__device__ __forceinline__ void gemm_fn(const u16* __restrict__ z1b, float4* __restrict__ Pb,
                                        const bf8 (&af)[2][3], const u32 (&owA)[4], const f4 (&lb4)[2],
                                        const int w, const int m, const int qd)
{
    #pragma unroll
    for (int G = 0; G < 4; ++G) {
        bf8 zb[3];
        #pragma unroll
        for (int s = 0; s < 3; ++s)
            zb[s] = *(const bf8*)(&z1b[(G*16 + m)*ZSTR + s*32 + qd*8]);

        f4 acc_t[2] = {lb4[0], lb4[1]};
        #pragma unroll
        for (int s = 0; s < 3; ++s)
            #pragma unroll
            for (int tt = 0; tt < 2; ++tt)
                acc_t[tt] = __builtin_amdgcn_mfma_f32_16x16x32_bf16(af[tt][s], zb[s], acc_t[tt], 0, 0, 0);

        // tile-row 4q+r of tile tt = local feature 8q+r+4tt -> lane (qd,m) holds exactly
        // B-frag k=8qd+j (local features 8qd..8qd+7) of board m: in-lane, no staging.
        union { u32 u[4]; h8 v; } bu, au;
        bu.u[0] = pkh(fmaxf(acc_t[0][0], 0.f), fmaxf(acc_t[0][1], 0.f));
        bu.u[1] = pkh(fmaxf(acc_t[0][2], 0.f), fmaxf(acc_t[0][3], 0.f));
        bu.u[2] = pkh(fmaxf(acc_t[1][0], 0.f), fmaxf(acc_t[1][1], 0.f));
        bu.u[3] = pkh(fmaxf(acc_t[1][2], 0.f), fmaxf(acc_t[1][3], 0.f));
        au.u[0] = owA[0]; au.u[1] = owA[1]; au.u[2] = owA[2]; au.u[3] = owA[3];
        f4 acc2 = {0.f, 0.f, 0.f, 0.f};
        acc2 = __builtin_amdgcn_mfma_f32_16x16x32_f16(au.v, bu.v, acc2, 0, 0, 0);
        if (qd == 0)
            Pb[(G*8 + w)*16 + m] = make_float4(acc2[0], acc2[1], acc2[2], acc2[3]);
    }
}

// ---- waves 4-7: softmax + flip-permute + store; lane (qd,m) -> board base + qd*16 + m ----
__device__ __forceinline__ void epi_fn(const float4* __restrict__ Pb, const u32 fl, const float4 obv,
                                       float* __restrict__ out, const int base, const int m, const int qd)
{
    float L0 = obv.x, L1 = obv.y, L2 = obv.z, L3 = obv.w;
    #pragma unroll
    for (int p = 0; p < 8; ++p) {
        float4 s = Pb[(qd*8 + p)*16 + m];
        L0 += s.x; L1 += s.y; L2 += s.z; L3 += s.w;
    }
    float mx = fmaxf(fmaxf(L0, L1), fmaxf(L2, L3));
    float e0 = __expf(L0 - mx), e1 = __expf(L1 - mx), e2 = __expf(L2 - mx), e3 = __expf(L3 - mx);
    float inv = __builtin_amdgcn_rcpf(e0 + e1 + e2 + e3);
    float p0 = e0 * inv, p1 = e1 * inv, p2 = e2 * inv, p3 = e3 * inv;
    float4 o;
    o.x = (fl & 1u) ? p1 : p0;
    o.y = (fl & 1u) ? p0 : p1;
    o.z = (fl & 2u) ? p3 : p2;
    o.w = (fl & 2u) ? p2 : p3;
    *(float4*)(out + (size_t)(base + qd*16 + m) * 4) = o;
}

__launch_bounds__(512, 4)
__global__ void smartcnn_fused(const int* __restrict__ exps,
                               const float* __restrict__ c0w, const float* __restrict__ c0b,
                               const float* __restrict__ c1w,
                               const float* __restrict__ lw,  const float* __restrict__ lb,
                               const float* __restrict__ ow,  const float* __restrict__ ob,
                               float* __restrict__ out)
{
    __shared__ uint2  ThA[121];
    __shared__ uint2  TvA[121];
    __shared__ u16    z1A[64 * ZSTR];    // static names: no dynamic-index demotion (R8 lesson)
    __shared__ u16    z1B[64 * ZSTR];
    __shared__ float4 PbA[32 * 16];      // [(G*8 + w)*16 + m]
    __shared__ float4 PbB[32 * 16];
    __shared__ u32    flgA[64];
    __shared__ u32    flgB[64];

    const int tid  = threadIdx.x;
    const int w    = tid >> 6;           // 0..7: wave w owns features 32w..32w+31
    const int lane = tid & 63;
    const int m    = lane & 15;
    const int qd   = lane >> 4;
    const bool isP = (w < 4);            // producer waves: phase1; waves 4-7: epilogue

    // ---- packed-channel pair tables ----
    for (int i = tid; i < 121; i += 512) {
        int v1 = i / 11, v2 = i - v1 * 11;
        float hv[4], vv[4];
        #pragma unroll
        for (int c = 0; c < 4; ++c) {
            hv[c] = fmaxf(c0w[c*24 + 0] + c0w[c*24 + (1+v1)*2 + 0] + c0b[c]
                        + c0w[c*24 + 1] + c0w[c*24 + (1+v2)*2 + 1], 0.f);
            vv[c] = fmaxf(c1w[c*24 + 0] + c1w[c*24 + (1+v1)*2 + 0]
                        + c1w[c*24 + 1] + c1w[c*24 + (1+v2)*2 + 1], 0.f);
        }
        ThA[i] = make_uint2(pk2(hv[0], hv[1]), pk2(hv[2], hv[3]));
        TvA[i] = make_uint2(pk2(vv[0], vv[1]), pk2(vv[2], vv[3]));
    }

    // ---- W1 A-fragments (24 VGPR): 32-feature slice, K-permuted + M-permuted ----
    // Staged through this wave's own z1 rows (waves 0-3: z1A; 4-7: z1B). Same-wave DS
    // ordering makes the staging-read -> later overwrite WAR-safe; cross-wave z1B reuse
    // (phase1 it+1) happens only after the setup barrier. FULLY UNROLLED (R8 lesson).
    bf8 af[2][3];
    {
        u16* srow = isP ? &z1A[(w*16 + m) * ZSTR] : &z1B[((w-4)*16 + m) * ZSTR];
        #pragma unroll
        for (int tt = 0; tt < 2; ++tt) {
            const int fid = 32*w + 8*(m >> 2) + (m & 3) + 4*tt;   // M-permuted feature row
            const float* rowp = lw + (size_t)fid*96 + qd*24;
            #pragma unroll
            for (int v = 0; v < 6; ++v) {
                float4 x = *(const float4*)(rowp + v*4);
                u16 e[4] = {(u16)bfr(x.x), (u16)bfr(x.y), (u16)bfr(x.z), (u16)bfr(x.w)};
                #pragma unroll
                for (int j = 0; j < 4; ++j) {
                    int ko = qd*24 + v*4 + j;
                    int kp = (ko < 48) ? ((ko % 12)*4 + ko/12)
                                       : (48 + ((ko - 48) % 12)*4 + (ko - 48)/12);
                    srow[kp] = e[j];
                }
            }
            #pragma unroll
            for (int s = 0; s < 3; ++s)
                af[tt][s] = *(const bf8*)(srow + s*32 + qd*8);
        }
    }
    // ---- out_w A-frag, fp16 (4 VGPR): K = this wave's 32 features, canonical order ----
    u32 owA[4];
    #pragma unroll
    for (int k = 0; k < 4; ++k)
        owA[k] = (m < 4) ? pkh(ow[m*256 + 32*w + 8*qd + 2*k], ow[m*256 + 32*w + 8*qd + 2*k + 1]) : 0u;
    // ---- linear_b (8 VGPR), M-permuted: lb4[tt][r] = lb[32w + 4tt + 8qd + r] ----
    f4 lb4[2];
    lb4[0] = *(const f4*)(lb + 32*w + 8*qd);
    lb4[1] = *(const f4*)(lb + 32*w + 8*qd + 4);
    const float4 obv = *(const float4*)ob;

    const int b0 = blockIdx.x * (ITERS * 64);
    __syncthreads();  // tables + all staging done before z1A/z1B reuse

    // ---- pre-loop: waves 0-3 build it0 -> A ----
    int4 e4;
    if (isP) {
        e4 = *(const int4*)(exps + (size_t)(b0 + w*16 + m)*16 + qd*4);
        phase1_fn(e4, z1A, flgA, &ThA[0], &TvA[0], w, m, qd);
        e4 = *(const int4*)(exps + (size_t)(b0 + 64 + w*16 + m)*16 + qd*4);
    }
    __syncthreads();  // z1A/flgA(it0) published

    u32 flA = 0, flB = 0;

    // H0: producers build it1->B; consumers hoist flg(it0); all gemm(it0 on A)
    if (isP) {
        phase1_fn(e4, z1B, flgB, &ThA[0], &TvA[0], w, m, qd);
        e4 = *(const int4*)(exps + (size_t)(b0 + 2*64 + w*16 + m)*16 + qd*4);
    } else {
        flA = flgA[qd*16 + m];
    }
    gemm_fn(z1A, PbA, af, owA, lb4, w, m, qd);
    __syncthreads();  // PbA(it0) + z1B/flgB(it1) published; z1A readers retired

    // H1: producers build it2->A; consumers epi(it0) + hoist flg(it1); all gemm(it1 on B)
    if (isP) {
        phase1_fn(e4, z1A, flgA, &ThA[0], &TvA[0], w, m, qd);
        e4 = *(const int4*)(exps + (size_t)(b0 + 3*64 + w*16 + m)*16 + qd*4);
    } else {
        epi_fn(PbA, flA, obv, out, b0 + 0*64, m, qd);
        flB = flgB[qd*16 + m];
    }
    gemm_fn(z1B, PbB, af, owA, lb4, w, m, qd);
    __syncthreads();  // PbB(it1) + z1A/flgA(it2) published; z1B readers retired

    // H2: producers build it3->B; consumers epi(it1) + hoist flg(it2); all gemm(it2 on A)
    if (isP) {
        phase1_fn(e4, z1B, flgB, &ThA[0], &TvA[0], w, m, qd);
    } else {
        epi_fn(PbB, flB, obv, out, b0 + 1*64, m, qd);
        flA = flgA[qd*16 + m];
    }
    gemm_fn(z1A, PbA, af, owA, lb4, w, m, qd);
    __syncthreads();  // PbA(it2) + z1B/flgB(it3) published; z1A readers retired

    // H3: consumers epi(it2) + hoist flg(it3); all gemm(it3 on B)
    if (!isP) {
        epi_fn(PbA, flA, obv, out, b0 + 2*64, m, qd);
        flB = flgB[qd*16 + m];
    }
    gemm_fn(z1B, PbB, af, owA, lb4, w, m, qd);
    __syncthreads();  // PbB(it3) published

    // drain
    if (!isP)
        epi_fn(PbB, flB, obv, out, b0 + 3*64, m, qd);
}

extern "C" void kernel_launch(void* const* d_in, const int* in_sizes, int n_in,
                              void* d_out, int out_size, void* d_ws, size_t ws_size,
                              hipStream_t stream) {
    const int*   exps = (const int*)  d_in[0];
    const float* c0w  = (const float*)d_in[1];
    const float* c0b  = (const float*)d_in[2];
    const float* c1w  = (const float*)d_in[3];
    const float* lw   = (const float*)d_in[4];
    const float* lbv  = (const float*)d_in[5];
    const float* oww  = (const float*)d_in[6];
    const float* obv  = (const float*)d_in[7];
    smartcnn_fused<<<NBLK, 512, 0, stream>>>(exps, c0w, c0b, c1w, lw, lbv, oww, obv, (float*)d_out);
}